// Round 13
// baseline (218.801 us; speedup 1.0000x reference)
//
#include <hip/hip_runtime.h>
#include <hip/hip_bf16.h>
#include <stdint.h>

typedef unsigned short u16;
typedef float f32x4 __attribute__((ext_vector_type(4)));
typedef short s16x8 __attribute__((ext_vector_type(8)));
typedef u16   u16x8 __attribute__((ext_vector_type(8)));
typedef u16   u16x4 __attribute__((ext_vector_type(4)));
typedef uint32_t u32x4 __attribute__((ext_vector_type(4)));

#define B_      4096
#define D_      256
#define NA_     131072
#define NM_     32768
#define N2_     8192
#define THR4    6.2499950e-6f   /* (0.05 - 1e-8)^4 */
#define K2E     14.426950408889634f  /* 10*log2(e) */
#define LN2_    0.6931471805599453f
#define CAPG    96
#define CAPS    40

// fuseB role interleave (Bresenham spread): S=segmean G=gemm T=tfix
#define NS_   1024
#define NG_   2080
#define NT_   256
#define NTOT_ 3360
#define NR_   2336   /* NTOT_ - NS_ */

// ---- workspace layout (bytes) ----
#define OFF_CNT_G   0u          // 4096 int
#define OFF_CNT_S   16384u      // 4096 int
#define OFF_NB      32768u      // 4096 int
#define OFF_SCAL    49152u      // f32[0]=llocal f32[1]=lsc int[3]=batch_max
#define OFF_S       65536u      // 8192 f32, atomically accumulated by gemm
#define ZERO_BYTES  98304u      // all of the above zeroed each call
#define OFF_T       98304u      // 8192 f32 (fully written by tfix)
#define OFF_C       131072u     // 8192 int (fully written by tfix)
#define OFF_PLIST   163840u     // 4096*32 int
#define OFF_LIST_G  688128u     // 4096*96 int
#define OFF_LIST_S  2260992u    // 4096*40 int
#define OFF_E       2916352u    // 8192*256 bf16 = 4 MB
#define WS_SMALL    7110656u
// big mode: bf16 copies of fg/fm for the gather
#define OFF_FGB     7110656u    // 131072*256 bf16 = 64 MB
#define OFF_FMB     74219520u   // 32768*256 bf16 = 16 MB
#define WS_BIG      90996736u

__device__ inline float wave_sum(float v) {
#pragma unroll
  for (int m = 1; m < 64; m <<= 1) v += __shfl_xor(v, m, 64);
  return v;
}
__device__ inline int wave_sum_i(int v) {
#pragma unroll
  for (int m = 1; m < 64; m <<= 1) v += __shfl_xor(v, m, 64);
  return v;
}
__device__ inline u16 f2bf(float f) {
  uint32_t u = __float_as_uint(f);
  uint32_t r = (u + 0x7FFFu + ((u >> 16) & 1u)) >> 16;
  return (u16)r;
}
__device__ inline float bf2f(u16 v) { return __uint_as_float(((uint32_t)v) << 16); }

__device__ inline f32x4 ldnt4(const float* p) {
  return __builtin_nontemporal_load((const f32x4*)(p));
}
__device__ inline u16x8 ldnt8(const u16* p) {
  return __builtin_nontemporal_load((const u16x8*)(p));
}

__device__ inline void gload16(const u16* __restrict__ g, u16* l) {
  __builtin_amdgcn_global_load_lds(
      (const __attribute__((address_space(1))) uint32_t*)g,
      (__attribute__((address_space(3))) uint32_t*)l, 16, 0, 0);
}

// ---- zero counters + S ----
__global__ void k_zero(u32x4* __restrict__ p) {
  u32x4 z = {0u, 0u, 0u, 0u};
  p[blockIdx.x * 256 + threadIdx.x] = z;   // 24*256*16B = 98304 B
}

// ---- fuseA roles (Bresenham-peeled): append(512) | pairs(256) | norm(2048) |
//      lsc(2048) | [big only:] convG(2048) | convM(512) ----
__global__ __launch_bounds__(256) void k_fuseA(
    const int* __restrict__ bg, const int* __restrict__ bs,
    int* __restrict__ cntg, int* __restrict__ cnts, int* __restrict__ bmax,
    int* __restrict__ listg, int* __restrict__ lists,
    const float* __restrict__ gm, const float* __restrict__ scm,
    const float* __restrict__ scs, const float* __restrict__ shp,
    const float* __restrict__ pp,
    const float* __restrict__ fg, const float* __restrict__ fm,
    u16* __restrict__ fgb, u16* __restrict__ fmb,
    u16* __restrict__ E, int* __restrict__ nb, int* __restrict__ plist,
    float* __restrict__ scal, int big) {
  int t = threadIdx.x, w = t >> 6, lane = t & 63;
  int blk = blockIdx.x;
  int ntot = big ? 7424 : 4864;

  { // ---- append (512): bucket lists + batch max ----
    int64_t p = (int64_t)blk * 512;
    int rem = (int)(p % ntot);
    if (rem < 512) {
      int aid = (int)(p / ntot);
      int i = aid * 256 + t;
      int b = -1;
      if (i < NA_) {
        b = bg[i];
        int pos = atomicAdd(&cntg[b], 1);
        if (pos < CAPG) listg[b * CAPG + pos] = i;
      }
      if (i < NM_) {
        int b2 = bs[i];
        int pos = atomicAdd(&cnts[b2], 1);
        if (pos < CAPS) lists[b2 * CAPS + pos] = i;
      }
      int m = b;
#pragma unroll
      for (int k = 1; k < 64; k <<= 1) m = max(m, __shfl_xor(m, k, 64));
      if ((t & 63) == 0 && m >= 0) atomicMax(bmax, m);
      return;
    }
    blk -= (int)((p + ntot - 1) / ntot);
    ntot -= 512;
  }

  { // ---- pairs (256): tiled, 16 a's per block ----
    int64_t p = (int64_t)blk * 256;
    int rem = (int)(p % ntot);
    if (rem < 256) {
      int pid = (int)(p / ntot);
      int a0 = pid * 16;
      __shared__ f32x4 pa_s[16];
      if (t < 16) pa_s[t] = *(const f32x4*)(pp + (size_t)(a0 + t) * 4);
      __syncthreads();
      for (int it = 0; it < 16; ++it) {
        int b = it * 256 + t;
        f32x4 pb = *(const f32x4*)(pp + (size_t)b * 4);
#pragma unroll
        for (int j = 0; j < 16; ++j) {
          f32x4 pa = pa_s[j];
          float dx = pa.x - pb.x, dy = pa.y - pb.y, dz = pa.z - pb.z, dw = pa.w - pb.w;
          float d2 = dx * dx + dy * dy + dz * dz + dw * dw;
          if (d2 < THR4) {
            int a = a0 + j;
            int pos = atomicAdd(&nb[a], 1);
            if (pos < 32) plist[a * 32 + pos] = b;
          }
        }
      }
      return;
    }
    blk -= (int)((p + ntot - 1) / ntot);
    ntot -= 256;
  }

  { // ---- norm (2048): normalize -> E bf16 ----
    int64_t p = (int64_t)blk * 2048;
    int rem = (int)(p % ntot);
    if (rem < 2048) {
      int nid = (int)(p / ntot);
      int r = nid * 4 + w;
      const float* src = (r < B_) ? gm + (size_t)r * D_ : scm + (size_t)(r - B_) * D_;
      f32x4 v = ldnt4(src + lane * 4);
      float ss = v.x * v.x + v.y * v.y + v.z * v.z + v.w * v.w;
      ss = wave_sum(ss);
      float inv = 1.f / fmaxf(sqrtf(ss), 1e-12f);
      u16x4 o;
      o.x = f2bf(v.x * inv); o.y = f2bf(v.y * inv);
      o.z = f2bf(v.z * inv); o.w = f2bf(v.w * inv);
      *(u16x4*)(E + (size_t)r * D_ + lane * 4) = o;
      return;
    }
    blk -= (int)((p + ntot - 1) / ntot);
    ntot -= 2048;
  }

  { // ---- lsc (2048, streaming NT) ----
    int64_t p = (int64_t)blk * 2048;
    int rem = (int)(p % ntot);
    if (rem < 2048) {
      int lid = (int)(p / ntot);
      int wg = lid * 4 + w;
      float acc = 0.f;
      for (int r = wg; r < NM_; r += 8192) {
        f32x4 va = ldnt4(scs + (size_t)r * D_ + lane * 4);
        f32x4 vb = ldnt4(shp + (size_t)r * D_ + lane * 4);
        float dx = va.x - vb.x, dy = va.y - vb.y, dz = va.z - vb.z, dw = va.w - vb.w;
        float ss = wave_sum(dx * dx + dy * dy + dz * dz + dw * dw);
        if (lane == 0) acc += sqrtf(ss);
      }
      __shared__ float sr4[4];
      if (lane == 0) sr4[w] = acc;
      __syncthreads();
      if (t == 0) atomicAdd(&scal[1], sr4[0] + sr4[1] + sr4[2] + sr4[3]);
      return;
    }
    blk -= (int)((p + ntot - 1) / ntot);
    ntot -= 2048;
  }

  { // ---- convG (2048, big only): fg f32 -> fgb bf16, 64 rows/block ----
    int64_t p = (int64_t)blk * 2048;
    int rem = (int)(p % ntot);
    if (rem < 2048) {
      int cid = (int)(p / ntot);
#pragma unroll 4
      for (int rr = 0; rr < 16; ++rr) {
        int row = cid * 64 + w * 16 + rr;
        f32x4 v = ldnt4(fg + (size_t)row * D_ + lane * 4);
        u16x4 o;
        o.x = f2bf(v.x); o.y = f2bf(v.y); o.z = f2bf(v.z); o.w = f2bf(v.w);
        *(u16x4*)(fgb + (size_t)row * D_ + lane * 4) = o;
      }
      return;
    }
    blk -= (int)((p + ntot - 1) / ntot);
    ntot -= 2048;
  }

  { // ---- convM (512 remainder, big only): fm -> fmb ----
#pragma unroll 4
    for (int rr = 0; rr < 16; ++rr) {
      int row = blk * 64 + w * 16 + rr;
      f32x4 v = ldnt4(fm + (size_t)row * D_ + lane * 4);
      u16x4 o;
      o.x = f2bf(v.x); o.y = f2bf(v.y); o.z = f2bf(v.z); o.w = f2bf(v.w);
      *(u16x4*)(fmb + (size_t)row * D_ + lane * 4) = o;
    }
  }
}

// ---- f32 gather (small mode) ----
__device__ inline void wave_row_sum(const float* __restrict__ src,
                                    const int* __restrict__ list,
                                    int off, int cnt, int lane, f32x4* accs) {
  f32x4 a0 = {0.f,0.f,0.f,0.f}, a1 = a0, a2 = a0, a3 = a0;
  f32x4 a4 = a0, a5 = a0, a6 = a0, a7 = a0;
  for (int base = 0; base < cnt; base += 64) {
    int n = min(cnt - base, 64);
    int idx = (lane < n) ? list[off + base + lane] : 0;
    int k = 0;
    for (; k + 7 < n; k += 8) {
      int i0 = __shfl(idx, k,     64), i1 = __shfl(idx, k + 1, 64);
      int i2 = __shfl(idx, k + 2, 64), i3 = __shfl(idx, k + 3, 64);
      int i4 = __shfl(idx, k + 4, 64), i5 = __shfl(idx, k + 5, 64);
      int i6 = __shfl(idx, k + 6, 64), i7 = __shfl(idx, k + 7, 64);
      a0 += ldnt4(src + (size_t)i0 * D_ + lane * 4);
      a1 += ldnt4(src + (size_t)i1 * D_ + lane * 4);
      a2 += ldnt4(src + (size_t)i2 * D_ + lane * 4);
      a3 += ldnt4(src + (size_t)i3 * D_ + lane * 4);
      a4 += ldnt4(src + (size_t)i4 * D_ + lane * 4);
      a5 += ldnt4(src + (size_t)i5 * D_ + lane * 4);
      a6 += ldnt4(src + (size_t)i6 * D_ + lane * 4);
      a7 += ldnt4(src + (size_t)i7 * D_ + lane * 4);
    }
    for (; k < n; k++) {
      int i0 = __shfl(idx, k, 64);
      a0 += ldnt4(src + (size_t)i0 * D_ + lane * 4);
    }
  }
  *accs = ((a0 + a1) + (a2 + a3)) + ((a4 + a5) + (a6 + a7));
}

#define BF8ADD(vv, okk, LL, HH)                                              \
  if (okk) {                                                                 \
    LL.x += bf2f(vv[0]); LL.y += bf2f(vv[1]); LL.z += bf2f(vv[2]); LL.w += bf2f(vv[3]); \
    HH.x += bf2f(vv[4]); HH.y += bf2f(vv[5]); HH.z += bf2f(vv[6]); HH.w += bf2f(vv[7]); \
  }

// ---- bf16 gather (big mode): 16B/lane covers 2 rows; lanes<32 even entries,
//      lanes>=32 odd. Result: dims (lane&31)*8..+7 duplicated across halves.
__device__ inline void wave_row_sum_b16(const u16* __restrict__ src,
                                        const int* __restrict__ list,
                                        int off, int cnt, int lane,
                                        f32x4* lo, f32x4* hi) {
  f32x4 z = {0.f, 0.f, 0.f, 0.f};
  f32x4 l0 = z, l1 = z, l2 = z, l3 = z, h0 = z, h1 = z, h2 = z, h3 = z;
  int half = lane >> 5;
  int dl = lane & 31;
  for (int base = 0; base < cnt; base += 64) {
    int n = min(cnt - base, 64);
    int idx = (lane < n) ? list[off + base + lane] : 0;
    int npair = (n + 1) >> 1;
    int j = 0;
    for (; j + 7 < npair; j += 8) {
      int e0 = 2 * j + half;
      int i0 = __shfl(idx, e0,      64), i1 = __shfl(idx, e0 + 2,  64);
      int i2 = __shfl(idx, e0 + 4,  64), i3 = __shfl(idx, e0 + 6,  64);
      int i4 = __shfl(idx, e0 + 8,  64), i5 = __shfl(idx, e0 + 10, 64);
      int i6 = __shfl(idx, e0 + 12, 64), i7 = __shfl(idx, e0 + 14, 64);
      u16x8 v0 = ldnt8(src + (size_t)i0 * D_ + dl * 8);
      u16x8 v1 = ldnt8(src + (size_t)i1 * D_ + dl * 8);
      u16x8 v2 = ldnt8(src + (size_t)i2 * D_ + dl * 8);
      u16x8 v3 = ldnt8(src + (size_t)i3 * D_ + dl * 8);
      u16x8 v4 = ldnt8(src + (size_t)i4 * D_ + dl * 8);
      u16x8 v5 = ldnt8(src + (size_t)i5 * D_ + dl * 8);
      u16x8 v6 = ldnt8(src + (size_t)i6 * D_ + dl * 8);
      u16x8 v7 = ldnt8(src + (size_t)i7 * D_ + dl * 8);
      BF8ADD(v0, e0      < n, l0, h0); BF8ADD(v1, e0 + 2  < n, l1, h1);
      BF8ADD(v2, e0 + 4  < n, l2, h2); BF8ADD(v3, e0 + 6  < n, l3, h3);
      BF8ADD(v4, e0 + 8  < n, l0, h0); BF8ADD(v5, e0 + 10 < n, l1, h1);
      BF8ADD(v6, e0 + 12 < n, l2, h2); BF8ADD(v7, e0 + 14 < n, l3, h3);
    }
    for (; j < npair; j++) {
      int e = 2 * j + half;
      int i0 = __shfl(idx, e, 64);
      u16x8 v = ldnt8(src + (size_t)i0 * D_ + dl * 8);
      BF8ADD(v, e < n, l0, h0);
    }
  }
  f32x4 L = (l0 + l1) + (l2 + l3), H = (h0 + h1) + (h2 + h3);
  L.x += __shfl_xor(L.x, 32, 64); L.y += __shfl_xor(L.y, 32, 64);
  L.z += __shfl_xor(L.z, 32, 64); L.w += __shfl_xor(L.w, 32, 64);
  H.x += __shfl_xor(H.x, 32, 64); H.y += __shfl_xor(H.y, 32, 64);
  H.z += __shfl_xor(H.z, 32, 64); H.w += __shfl_xor(H.w, 32, 64);
  *lo = L; *hi = H;
}

// ---- fuseB: segmean | gemm (BK=32) | tfix, Bresenham-interleaved ----
__global__ __launch_bounds__(256) void k_fuseB(
    const u16* __restrict__ E,
    const float* __restrict__ fg, const float* __restrict__ fm,
    const u16* __restrict__ fgb, const u16* __restrict__ fmb,
    const int* __restrict__ cntg, const int* __restrict__ cnts,
    const int* __restrict__ listg, const int* __restrict__ lists,
    const int* __restrict__ nb, const int* __restrict__ plist,
    float* __restrict__ S, float* __restrict__ T, int* __restrict__ C,
    float* __restrict__ scal, int big) {
  __shared__ __align__(16) u16 As[128 * 32];
  __shared__ __align__(16) u16 Bs[128 * 32];
  int blk = blockIdx.x;
  int tid = threadIdx.x, lane = tid & 63, wid = tid >> 6;

  int64_t p = (int64_t)blk * NS_;
  int srem = (int)(p % NTOT_);
  if (srem < NS_) {               // ---- segmean ----
    int sid = (int)(p / NTOT_);
    int b = sid * 4 + wid;
    int cg = cntg[b], cs = cnts[b];
    float loc;
    if (big) {
      f32x4 gl, gh, sl, sh;
      wave_row_sum_b16(fgb, listg, b * CAPG, min(cg, CAPG), lane, &gl, &gh);
      wave_row_sum_b16(fmb, lists, b * CAPS, min(cs, CAPS), lane, &sl, &sh);
      float ig = 1.f / fmaxf((float)cg, 1.f);
      float is = 1.f / fmaxf((float)cs, 1.f);
      f32x4 d0 = gl * ig - sl * is;
      f32x4 d1 = gh * ig - sh * is;
      loc = d0.x * d0.x + d0.y * d0.y + d0.z * d0.z + d0.w * d0.w
          + d1.x * d1.x + d1.y * d1.y + d1.z * d1.z + d1.w * d1.w;
      loc = wave_sum(loc) * 0.5f;   // halves duplicated
    } else {
      f32x4 sg, ss;
      wave_row_sum(fg, listg, b * CAPG, min(cg, CAPG), lane, &sg);
      wave_row_sum(fm, lists, b * CAPS, min(cs, CAPS), lane, &ss);
      float ig = 1.f / fmaxf((float)cg, 1.f);
      float is = 1.f / fmaxf((float)cs, 1.f);
      float dx = sg.x * ig - ss.x * is, dy = sg.y * ig - ss.y * is;
      float dz = sg.z * ig - ss.z * is, dw = sg.w * ig - ss.w * is;
      loc = wave_sum(dx * dx + dy * dy + dz * dz + dw * dw);
    }
    __shared__ float r2[4];
    if (lane == 0) r2[wid] = (cg > 0 && cs > 0) ? sqrtf(loc) : 0.f;
    __syncthreads();
    if (tid == 0) {
      float s = r2[0] + r2[1] + r2[2] + r2[3];
      if (s != 0.f) atomicAdd(&scal[0], s);
    }
    return;
  }

  int r = blk - (int)((p + NTOT_ - 1) / NTOT_);   // rank among non-S
  int64_t q = (int64_t)r * NG_;
  int grem = (int)(q % NR_);

  if (grem >= NG_) {              // ---- tfix (8 rows/wave) ----
    int tix = r - (int)((q + NR_ - 1) / NR_);
#pragma unroll
    for (int k8 = 0; k8 < 8; k8++) {
      int i = tix * 32 + wid * 8 + k8;
      int a = i & (B_ - 1);
      int n = min(nb[a], 32);
      u16x4 vi = *(const u16x4*)(E + (size_t)i * D_ + lane * 4);
      float ex = bf2f(vi.x), ey = bf2f(vi.y), ez = bf2f(vi.z), ew = bf2f(vi.w);
      float acc = -(ex * ex + ey * ey + ez * ez + ew * ew);
      for (int k = 0; k < n; k++) {
        int b = plist[a * 32 + k];
        u16x4 v1 = *(const u16x4*)(E + (size_t)b * D_ + lane * 4);
        u16x4 v2 = *(const u16x4*)(E + (size_t)(b + B_) * D_ + lane * 4);
        acc += ex * bf2f(v1.x) + ey * bf2f(v1.y) + ez * bf2f(v1.z) + ew * bf2f(v1.w);
        acc += ex * bf2f(v2.x) + ey * bf2f(v2.y) + ez * bf2f(v2.z) + ew * bf2f(v2.w);
      }
      acc = wave_sum(acc);
      if (lane == 0) { T[i] = 10.0f * acc; C[i] = 2 * n - 1; }
    }
    return;
  }

  // ---- gemm: triangular 128x128 tile, BK=32 chunks, global_load_lds staging ----
  int t = (int)(q / NR_);
  int bi = (int)((129.0f - sqrtf(129.0f * 129.0f - 8.0f * (float)t)) * 0.5f);
  while ((bi + 1) * (129 - (bi + 1)) / 2 <= t) bi++;
  while (bi * (129 - bi) / 2 > t) bi--;
  int bj = bi + (t - bi * (129 - bi) / 2);

  int row0 = bi * 128, col0 = bj * 128;
  int wr = wid >> 1, wc = wid & 1;

  int rsub = lane >> 2;                               // 0..15
  int csw  = (((lane & 3) ^ (rsub & 3)) << 3);        // swizzled col in u16 units

  f32x4 acc[4][4];
#pragma unroll
  for (int mi = 0; mi < 4; mi++)
#pragma unroll
    for (int ni = 0; ni < 4; ni++) {
      f32x4 z = {0.f, 0.f, 0.f, 0.f};
      acc[mi][ni] = z;
    }

  for (int kc = 0; kc < 8; ++kc) {
    __syncthreads();
#pragma unroll
    for (int it = 0; it < 2; it++) {
      int s = wid * 2 + it;                           // 0..7
      int rr = s * 16 + rsub;
      gload16(E + (size_t)(row0 + rr) * D_ + kc * 32 + csw, As + s * 512);
      gload16(E + (size_t)(col0 + rr) * D_ + kc * 32 + csw, Bs + s * 512);
    }
    __syncthreads();
    s16x8 af[4], bfr[4];
#pragma unroll
    for (int mi = 0; mi < 4; mi++) {
      int rA = wr * 64 + mi * 16 + (lane & 15);
      int addr = rA * 64 + (((lane >> 4) * 16) ^ ((rA & 3) << 4));
      af[mi] = *(const s16x8*)((const char*)As + addr);
    }
#pragma unroll
    for (int ni = 0; ni < 4; ni++) {
      int rB = wc * 64 + ni * 16 + (lane & 15);
      int addr = rB * 64 + (((lane >> 4) * 16) ^ ((rB & 3) << 4));
      bfr[ni] = *(const s16x8*)((const char*)Bs + addr);
    }
#pragma unroll
    for (int mi = 0; mi < 4; mi++)
#pragma unroll
      for (int ni = 0; ni < 4; ni++)
        acc[mi][ni] = __builtin_amdgcn_mfma_f32_16x16x32_bf16(af[mi], bfr[ni], acc[mi][ni], 0, 0, 0);
  }

  int g = lane >> 4, cl = lane & 15;
  float colsum[4] = {0.f, 0.f, 0.f, 0.f};
#pragma unroll
  for (int mi = 0; mi < 4; mi++) {
#pragma unroll
    for (int reg = 0; reg < 4; ++reg) {
      int gi = row0 + wr * 64 + mi * 16 + g * 4 + reg;
      float vs = 0.f;
#pragma unroll
      for (int ni = 0; ni < 4; ni++) {
        float e = exp2f(acc[mi][ni][reg] * K2E - K2E);
        vs += e;
        colsum[ni] += e;
      }
#pragma unroll
      for (int m = 1; m < 16; m <<= 1) vs += __shfl_xor(vs, m, 64);
      if (cl == 0) atomicAdd(&S[gi], vs);
    }
  }
  if (bi != bj) {
#pragma unroll
    for (int ni = 0; ni < 4; ni++) {
      float cs = colsum[ni];
      cs += __shfl_xor(cs, 16, 64);
      cs += __shfl_xor(cs, 32, 64);
      if (g == 0) atomicAdd(&S[col0 + wc * 64 + ni * 16 + cl], cs);
    }
  }
}

// ---- final combine (+ l_prop fused) ----
__global__ void k_final(const float* __restrict__ S, const float* __restrict__ T,
                        const int* __restrict__ C, const float* __restrict__ scal,
                        const float* __restrict__ pp, const float* __restrict__ pt,
                        float* __restrict__ out) {
  float sp = 0.f;
  for (int i = threadIdx.x; i < B_ * 4; i += 256) {
    float d = pp[i] - pt[i];
    sp += d * d;
  }
  float rls = 0.f; int nv = 0;
  for (int i = threadIdx.x; i < N2_; i += 256) {
    int ci = C[i];
    if (ci > 0) { rls += (10.0f + __log2f(S[i]) * LN2_) - T[i] / (float)ci; nv++; }
  }
  rls = wave_sum(rls);
  sp  = wave_sum(sp);
  nv  = wave_sum_i(nv);
  __shared__ float r1[4], r3[4]; __shared__ int r2[4];
  int lane = threadIdx.x & 63, w = threadIdx.x >> 6;
  if (lane == 0) { r1[w] = rls; r2[w] = nv; r3[w] = sp; }
  __syncthreads();
  if (threadIdx.x == 0) {
    float rtot = r1[0] + r1[1] + r1[2] + r1[3];
    int nvt = r2[0] + r2[1] + r2[2] + r2[3];
    float sptot = r3[0] + r3[1] + r3[2] + r3[3];
    float l_contr = nvt > 0 ? rtot / (float)nvt : 0.f;
    int bmax = ((const int*)scal)[3];
    float bs = (float)bmax + 1.0f;
    float l_local_g = scal[0] / bs;
    float l_sc = scal[1] / (float)NM_;
    float l_prop = sptot / (float)(B_ * 4);
    float l_hes = 1.0f * l_local_g + 0.8f * l_contr + 1.0f * l_sc + 0.8f * l_contr + 0.5f * l_prop;
    out[0] = l_hes; out[1] = l_local_g; out[2] = l_contr;
    out[3] = l_sc;  out[4] = l_contr;   out[5] = l_prop;
  }
}

extern "C" void kernel_launch(void* const* d_in, const int* in_sizes, int n_in,
                              void* d_out, int out_size, void* d_ws, size_t ws_size,
                              hipStream_t stream) {
  if (ws_size < WS_SMALL) return;
  int big = (ws_size >= WS_BIG) ? 1 : 0;

  const float* gm  = (const float*)d_in[0];
  const float* fg  = (const float*)d_in[1];
  const float* scm = (const float*)d_in[2];
  const float* scs = (const float*)d_in[3];
  const float* mot = (const float*)d_in[4];
  const float* shp = (const float*)d_in[5];
  const float* pp  = (const float*)d_in[6];
  const float* pt  = (const float*)d_in[7];
  const int* bg = (const int*)d_in[8];
  const int* bs = (const int*)d_in[9];
  float* out = (float*)d_out;
  char* ws = (char*)d_ws;

  int* cntg  = (int*)(ws + OFF_CNT_G);
  int* cnts  = (int*)(ws + OFF_CNT_S);
  int* nb    = (int*)(ws + OFF_NB);
  float* scal = (float*)(ws + OFF_SCAL);
  float* S   = (float*)(ws + OFF_S);
  float* T   = (float*)(ws + OFF_T);
  int* C     = (int*)(ws + OFF_C);
  int* plist = (int*)(ws + OFF_PLIST);
  int* listg = (int*)(ws + OFF_LIST_G);
  int* lists = (int*)(ws + OFF_LIST_S);
  u16* E     = (u16*)(ws + OFF_E);
  u16* fgb   = (u16*)(ws + OFF_FGB);   // valid only in big mode (never deref'd otherwise)
  u16* fmb   = (u16*)(ws + OFF_FMB);

  k_zero<<<24, 256, 0, stream>>>((u32x4*)ws);
  k_fuseA<<<big ? 7424 : 4864, 256, 0, stream>>>(
      bg, bs, cntg, cnts, (int*)scal + 3, listg, lists,
      gm, scm, scs, shp, pp, fg, mot, fgb, fmb, E, nb, plist, scal, big);
  k_fuseB<<<NTOT_, 256, 0, stream>>>(E, fg, mot, fgb, fmb, cntg, cnts,
                                     listg, lists, nb, plist, S, T, C, scal, big);
  k_final<<<1, 256, 0, stream>>>(S, T, C, scal, pp, pt, out);
}

// Round 14
// 211.850 us; speedup vs baseline: 1.0328x; 1.0328x over previous
//
#include <hip/hip_runtime.h>
#include <hip/hip_bf16.h>
#include <stdint.h>

typedef unsigned short u16;
typedef float f32x4 __attribute__((ext_vector_type(4)));
typedef short s16x8 __attribute__((ext_vector_type(8)));
typedef u16   u16x8 __attribute__((ext_vector_type(8)));
typedef u16   u16x4 __attribute__((ext_vector_type(4)));
typedef uint32_t u32x4 __attribute__((ext_vector_type(4)));

#define B_      4096
#define D_      256
#define NA_     131072
#define NM_     32768
#define N2_     8192
#define THR4    6.2499950e-6f   /* (0.05 - 1e-8)^4 */
#define K2E     14.426950408889634f  /* 10*log2(e) */
#define LN2_    0.6931471805599453f
#define CAPG    96
#define CAPS    40

// fuseB role interleave (Bresenham spread): S=segmean G=gemm T=tfix
#define NS_   1024
#define NG_   2080
#define NT_   256
#define NTOT_ 3360
#define NR_   2336   /* NTOT_ - NS_ */

// ---- workspace layout (bytes) ----
#define OFF_CNT_G   0u          // 4096 int
#define OFF_CNT_S   16384u      // 4096 int
#define OFF_NB      32768u      // 4096 int
#define OFF_SCAL    49152u      // f32[0]=llocal f32[1]=lsc int[3]=batch_max
#define OFF_S       65536u      // 8192 f32, atomically accumulated by gemm
#define ZERO_BYTES  98304u      // all of the above zeroed each call
#define OFF_T       98304u      // 8192 f32 (fully written by tfix)
#define OFF_C       131072u     // 8192 int (fully written by tfix)
#define OFF_PLIST   163840u     // 4096*32 int
#define OFF_LIST_G  688128u     // 4096*96 int
#define OFF_LIST_S  2260992u    // 4096*40 int
#define OFF_E       2916352u    // 8192*256 bf16 = 4 MB
#define WS_NEED     7110656u

__device__ inline float wave_sum(float v) {
#pragma unroll
  for (int m = 1; m < 64; m <<= 1) v += __shfl_xor(v, m, 64);
  return v;
}
__device__ inline int wave_sum_i(int v) {
#pragma unroll
  for (int m = 1; m < 64; m <<= 1) v += __shfl_xor(v, m, 64);
  return v;
}
__device__ inline u16 f2bf(float f) {
  uint32_t u = __float_as_uint(f);
  uint32_t r = (u + 0x7FFFu + ((u >> 16) & 1u)) >> 16;
  return (u16)r;
}
__device__ inline float bf2f(u16 v) { return __uint_as_float(((uint32_t)v) << 16); }

// non-temporal f32x4 load: keeps streaming data from evicting E out of L2
__device__ inline f32x4 ldnt4(const float* p) {
  return __builtin_nontemporal_load((const f32x4*)(p));
}

__device__ inline void gload16(const u16* __restrict__ g, u16* l) {
  __builtin_amdgcn_global_load_lds(
      (const __attribute__((address_space(1))) uint32_t*)g,
      (__attribute__((address_space(3))) uint32_t*)l, 16, 0, 0);
}

// ---- zero counters + S ----
__global__ void k_zero(u32x4* __restrict__ p) {
  u32x4 z = {0u, 0u, 0u, 0u};
  p[blockIdx.x * 256 + threadIdx.x] = z;   // 24*256*16B = 98304 B
}

// ---- fuseA (4864 blocks, Bresenham-peeled):
//      append(512) | pairs-tiled(256) | norm(2048) | lsc(2048) ----
__global__ __launch_bounds__(256) void k_fuseA(
    const int* __restrict__ bg, const int* __restrict__ bs,
    int* __restrict__ cntg, int* __restrict__ cnts, int* __restrict__ bmax,
    int* __restrict__ listg, int* __restrict__ lists,
    const float* __restrict__ gm, const float* __restrict__ scm,
    const float* __restrict__ scs, const float* __restrict__ shp,
    const float* __restrict__ pp,
    u16* __restrict__ E, int* __restrict__ nb, int* __restrict__ plist,
    float* __restrict__ scal) {
  int t = threadIdx.x, w = t >> 6, lane = t & 63;
  int blk = blockIdx.x;
  int ntot = 4864;

  { // ---- append (512): bucket lists + batch max ----
    int64_t p = (int64_t)blk * 512;
    int rem = (int)(p % ntot);
    if (rem < 512) {
      int aid = (int)(p / ntot);
      int i = aid * 256 + t;
      int b = -1;
      if (i < NA_) {
        b = bg[i];
        int pos = atomicAdd(&cntg[b], 1);
        if (pos < CAPG) listg[b * CAPG + pos] = i;
      }
      if (i < NM_) {
        int b2 = bs[i];
        int pos = atomicAdd(&cnts[b2], 1);
        if (pos < CAPS) lists[b2 * CAPS + pos] = i;
      }
      int m = b;
#pragma unroll
      for (int k = 1; k < 64; k <<= 1) m = max(m, __shfl_xor(m, k, 64));
      if ((t & 63) == 0 && m >= 0) atomicMax(bmax, m);
      return;
    }
    blk -= (int)((p + ntot - 1) / ntot);
    ntot -= 512;   // 4352
  }

  { // ---- pairs (256): tiled, 16 a's per block ----
    int64_t p = (int64_t)blk * 256;
    int rem = (int)(p % ntot);
    if (rem < 256) {
      int pid = (int)(p / ntot);
      int a0 = pid * 16;
      __shared__ f32x4 pa_s[16];
      if (t < 16) pa_s[t] = *(const f32x4*)(pp + (size_t)(a0 + t) * 4);
      __syncthreads();
      for (int it = 0; it < 16; ++it) {
        int b = it * 256 + t;
        f32x4 pb = *(const f32x4*)(pp + (size_t)b * 4);
#pragma unroll
        for (int j = 0; j < 16; ++j) {
          f32x4 pa = pa_s[j];
          float dx = pa.x - pb.x, dy = pa.y - pb.y, dz = pa.z - pb.z, dw = pa.w - pb.w;
          float d2 = dx * dx + dy * dy + dz * dz + dw * dw;
          if (d2 < THR4) {
            int a = a0 + j;
            int pos = atomicAdd(&nb[a], 1);
            if (pos < 32) plist[a * 32 + pos] = b;
          }
        }
      }
      return;
    }
    blk -= (int)((p + ntot - 1) / ntot);
    ntot -= 256;   // 4096
  }

  if (!(blk & 1)) {               // ---- norm (2048): normalize -> E bf16 ----
    int r = (blk >> 1) * 4 + w;
    const float* src = (r < B_) ? gm + (size_t)r * D_ : scm + (size_t)(r - B_) * D_;
    f32x4 v = ldnt4(src + lane * 4);
    float ss = v.x * v.x + v.y * v.y + v.z * v.z + v.w * v.w;
    ss = wave_sum(ss);
    float inv = 1.f / fmaxf(sqrtf(ss), 1e-12f);
    u16x4 o;
    o.x = f2bf(v.x * inv); o.y = f2bf(v.y * inv);
    o.z = f2bf(v.z * inv); o.w = f2bf(v.w * inv);
    *(u16x4*)(E + (size_t)r * D_ + lane * 4) = o;
  } else {                        // ---- lsc (2048, streaming NT) ----
    int wg = (blk >> 1) * 4 + w;
    float acc = 0.f;
    for (int r = wg; r < NM_; r += 8192) {
      f32x4 va = ldnt4(scs + (size_t)r * D_ + lane * 4);
      f32x4 vb = ldnt4(shp + (size_t)r * D_ + lane * 4);
      float dx = va.x - vb.x, dy = va.y - vb.y, dz = va.z - vb.z, dw = va.w - vb.w;
      float ss = wave_sum(dx * dx + dy * dy + dz * dz + dw * dw);
      if (lane == 0) acc += sqrtf(ss);
    }
    __shared__ float sr4[4];
    if (lane == 0) sr4[w] = acc;
    __syncthreads();
    if (t == 0) atomicAdd(&scal[1], sr4[0] + sr4[1] + sr4[2] + sr4[3]);
  }
}

// ---- wave-autonomous segmented mean gather (NT row loads) ----
__device__ inline void wave_row_sum(const float* __restrict__ src,
                                    const int* __restrict__ list,
                                    int off, int cnt, int lane, f32x4* accs) {
  f32x4 a0 = {0.f,0.f,0.f,0.f}, a1 = a0, a2 = a0, a3 = a0;
  f32x4 a4 = a0, a5 = a0, a6 = a0, a7 = a0;
  for (int base = 0; base < cnt; base += 64) {
    int n = min(cnt - base, 64);
    int idx = (lane < n) ? list[off + base + lane] : 0;
    int k = 0;
    for (; k + 7 < n; k += 8) {
      int i0 = __shfl(idx, k,     64), i1 = __shfl(idx, k + 1, 64);
      int i2 = __shfl(idx, k + 2, 64), i3 = __shfl(idx, k + 3, 64);
      int i4 = __shfl(idx, k + 4, 64), i5 = __shfl(idx, k + 5, 64);
      int i6 = __shfl(idx, k + 6, 64), i7 = __shfl(idx, k + 7, 64);
      a0 += ldnt4(src + (size_t)i0 * D_ + lane * 4);
      a1 += ldnt4(src + (size_t)i1 * D_ + lane * 4);
      a2 += ldnt4(src + (size_t)i2 * D_ + lane * 4);
      a3 += ldnt4(src + (size_t)i3 * D_ + lane * 4);
      a4 += ldnt4(src + (size_t)i4 * D_ + lane * 4);
      a5 += ldnt4(src + (size_t)i5 * D_ + lane * 4);
      a6 += ldnt4(src + (size_t)i6 * D_ + lane * 4);
      a7 += ldnt4(src + (size_t)i7 * D_ + lane * 4);
    }
    for (; k < n; k++) {
      int i0 = __shfl(idx, k, 64);
      a0 += ldnt4(src + (size_t)i0 * D_ + lane * 4);
    }
  }
  *accs = ((a0 + a1) + (a2 + a3)) + ((a4 + a5) + (a6 + a7));
}

// ---- fuseB: segmean | gemm (BK=32, 16.6KB LDS) | tfix, Bresenham-interleaved ----
__global__ __launch_bounds__(256) void k_fuseB(
    const u16* __restrict__ E,
    const float* __restrict__ fg, const float* __restrict__ fm,
    const int* __restrict__ cntg, const int* __restrict__ cnts,
    const int* __restrict__ listg, const int* __restrict__ lists,
    const int* __restrict__ nb, const int* __restrict__ plist,
    float* __restrict__ S, float* __restrict__ T, int* __restrict__ C,
    float* __restrict__ scal) {
  __shared__ __align__(16) u16 As[128 * 32];   // 8 KB
  __shared__ __align__(16) u16 Bs[128 * 32];   // 8 KB
  int blk = blockIdx.x;
  int tid = threadIdx.x, lane = tid & 63, wid = tid >> 6;

  int64_t p = (int64_t)blk * NS_;
  int srem = (int)(p % NTOT_);
  if (srem < NS_) {               // ---- segmean ----
    int sid = (int)(p / NTOT_);
    int b = sid * 4 + wid;
    int cg = cntg[b], cs = cnts[b];
    f32x4 sg, ss;
    wave_row_sum(fg, listg, b * CAPG, min(cg, CAPG), lane, &sg);
    wave_row_sum(fm, lists, b * CAPS, min(cs, CAPS), lane, &ss);
    float ig = 1.f / fmaxf((float)cg, 1.f);
    float is = 1.f / fmaxf((float)cs, 1.f);
    float dx = sg.x * ig - ss.x * is, dy = sg.y * ig - ss.y * is;
    float dz = sg.z * ig - ss.z * is, dw = sg.w * ig - ss.w * is;
    float v = wave_sum(dx * dx + dy * dy + dz * dz + dw * dw);
    __shared__ float r2[4];
    if (lane == 0) r2[wid] = (cg > 0 && cs > 0) ? sqrtf(v) : 0.f;
    __syncthreads();
    if (tid == 0) {
      float s = r2[0] + r2[1] + r2[2] + r2[3];
      if (s != 0.f) atomicAdd(&scal[0], s);
    }
    return;
  }

  int r = blk - (int)((p + NTOT_ - 1) / NTOT_);   // rank among non-S
  int64_t q = (int64_t)r * NG_;
  int grem = (int)(q % NR_);

  if (grem >= NG_) {              // ---- tfix (8 rows/wave) ----
    int tix = r - (int)((q + NR_ - 1) / NR_);
#pragma unroll
    for (int k8 = 0; k8 < 8; k8++) {
      int i = tix * 32 + wid * 8 + k8;
      int a = i & (B_ - 1);
      int n = min(nb[a], 32);
      u16x4 vi = *(const u16x4*)(E + (size_t)i * D_ + lane * 4);
      float ex = bf2f(vi.x), ey = bf2f(vi.y), ez = bf2f(vi.z), ew = bf2f(vi.w);
      float acc = -(ex * ex + ey * ey + ez * ez + ew * ew);
      for (int k = 0; k < n; k++) {
        int b = plist[a * 32 + k];
        u16x4 v1 = *(const u16x4*)(E + (size_t)b * D_ + lane * 4);
        u16x4 v2 = *(const u16x4*)(E + (size_t)(b + B_) * D_ + lane * 4);
        acc += ex * bf2f(v1.x) + ey * bf2f(v1.y) + ez * bf2f(v1.z) + ew * bf2f(v1.w);
        acc += ex * bf2f(v2.x) + ey * bf2f(v2.y) + ez * bf2f(v2.z) + ew * bf2f(v2.w);
      }
      acc = wave_sum(acc);
      if (lane == 0) { T[i] = 10.0f * acc; C[i] = 2 * n - 1; }
    }
    return;
  }

  // ---- gemm: triangular 128x128 tile, BK=32 chunks, global_load_lds staging ----
  int t = (int)(q / NR_);
  int bi = (int)((129.0f - sqrtf(129.0f * 129.0f - 8.0f * (float)t)) * 0.5f);
  while ((bi + 1) * (129 - (bi + 1)) / 2 <= t) bi++;
  while (bi * (129 - bi) / 2 > t) bi--;
  int bj = bi + (t - bi * (129 - bi) / 2);

  int row0 = bi * 128, col0 = bj * 128;
  int wr = wid >> 1, wc = wid & 1;

  // staging geometry: segment s (0..7) = 16 rows x 64B; lane -> row s*16+(lane>>2),
  // col bytes (lane&3)*16, source pre-swizzled by ((row&3)<<4)
  int rsub = lane >> 2;                               // 0..15
  int csw  = (((lane & 3) ^ (rsub & 3)) << 3);        // swizzled col in u16 units

  f32x4 acc[4][4];
#pragma unroll
  for (int mi = 0; mi < 4; mi++)
#pragma unroll
    for (int ni = 0; ni < 4; ni++) {
      f32x4 z = {0.f, 0.f, 0.f, 0.f};
      acc[mi][ni] = z;
    }

  for (int kc = 0; kc < 8; ++kc) {
    __syncthreads();
#pragma unroll
    for (int it = 0; it < 2; it++) {
      int s = wid * 2 + it;                           // 0..7
      int rr = s * 16 + rsub;
      gload16(E + (size_t)(row0 + rr) * D_ + kc * 32 + csw, As + s * 512);
      gload16(E + (size_t)(col0 + rr) * D_ + kc * 32 + csw, Bs + s * 512);
    }
    __syncthreads();
    s16x8 af[4], bfr[4];
#pragma unroll
    for (int mi = 0; mi < 4; mi++) {
      int rA = wr * 64 + mi * 16 + (lane & 15);
      int addr = rA * 64 + (((lane >> 4) * 16) ^ ((rA & 3) << 4));
      af[mi] = *(const s16x8*)((const char*)As + addr);
    }
#pragma unroll
    for (int ni = 0; ni < 4; ni++) {
      int rB = wc * 64 + ni * 16 + (lane & 15);
      int addr = rB * 64 + (((lane >> 4) * 16) ^ ((rB & 3) << 4));
      bfr[ni] = *(const s16x8*)((const char*)Bs + addr);
    }
#pragma unroll
    for (int mi = 0; mi < 4; mi++)
#pragma unroll
      for (int ni = 0; ni < 4; ni++)
        acc[mi][ni] = __builtin_amdgcn_mfma_f32_16x16x32_bf16(af[mi], bfr[ni], acc[mi][ni], 0, 0, 0);
  }

  // epilogue: exp(10a-10)=exp2(a*K2E-K2E); rows + (off-diag) cols -> atomic S
  int g = lane >> 4, cl = lane & 15;
  float colsum[4] = {0.f, 0.f, 0.f, 0.f};
#pragma unroll
  for (int mi = 0; mi < 4; mi++) {
#pragma unroll
    for (int reg = 0; reg < 4; ++reg) {
      int gi = row0 + wr * 64 + mi * 16 + g * 4 + reg;
      float vs = 0.f;
#pragma unroll
      for (int ni = 0; ni < 4; ni++) {
        float e = exp2f(acc[mi][ni][reg] * K2E - K2E);
        vs += e;
        colsum[ni] += e;
      }
#pragma unroll
      for (int m = 1; m < 16; m <<= 1) vs += __shfl_xor(vs, m, 64);
      if (cl == 0) atomicAdd(&S[gi], vs);
    }
  }
  if (bi != bj) {
#pragma unroll
    for (int ni = 0; ni < 4; ni++) {
      float cs = colsum[ni];
      cs += __shfl_xor(cs, 16, 64);
      cs += __shfl_xor(cs, 32, 64);
      if (g == 0) atomicAdd(&S[col0 + wc * 64 + ni * 16 + cl], cs);
    }
  }
}

// ---- final combine (+ l_prop fused) ----
__global__ void k_final(const float* __restrict__ S, const float* __restrict__ T,
                        const int* __restrict__ C, const float* __restrict__ scal,
                        const float* __restrict__ pp, const float* __restrict__ pt,
                        float* __restrict__ out) {
  float sp = 0.f;
  for (int i = threadIdx.x; i < B_ * 4; i += 256) {
    float d = pp[i] - pt[i];
    sp += d * d;
  }
  float rls = 0.f; int nv = 0;
  for (int i = threadIdx.x; i < N2_; i += 256) {
    int ci = C[i];
    if (ci > 0) { rls += (10.0f + __log2f(S[i]) * LN2_) - T[i] / (float)ci; nv++; }
  }
  rls = wave_sum(rls);
  sp  = wave_sum(sp);
  nv  = wave_sum_i(nv);
  __shared__ float r1[4], r3[4]; __shared__ int r2[4];
  int lane = threadIdx.x & 63, w = threadIdx.x >> 6;
  if (lane == 0) { r1[w] = rls; r2[w] = nv; r3[w] = sp; }
  __syncthreads();
  if (threadIdx.x == 0) {
    float rtot = r1[0] + r1[1] + r1[2] + r1[3];
    int nvt = r2[0] + r2[1] + r2[2] + r2[3];
    float sptot = r3[0] + r3[1] + r3[2] + r3[3];
    float l_contr = nvt > 0 ? rtot / (float)nvt : 0.f;
    int bmax = ((const int*)scal)[3];
    float bs = (float)bmax + 1.0f;
    float l_local_g = scal[0] / bs;
    float l_sc = scal[1] / (float)NM_;
    float l_prop = sptot / (float)(B_ * 4);
    float l_hes = 1.0f * l_local_g + 0.8f * l_contr + 1.0f * l_sc + 0.8f * l_contr + 0.5f * l_prop;
    out[0] = l_hes; out[1] = l_local_g; out[2] = l_contr;
    out[3] = l_sc;  out[4] = l_contr;   out[5] = l_prop;
  }
}

extern "C" void kernel_launch(void* const* d_in, const int* in_sizes, int n_in,
                              void* d_out, int out_size, void* d_ws, size_t ws_size,
                              hipStream_t stream) {
  if (ws_size < WS_NEED) return;
  const float* gm  = (const float*)d_in[0];
  const float* fg  = (const float*)d_in[1];
  const float* scm = (const float*)d_in[2];
  const float* scs = (const float*)d_in[3];
  const float* mot = (const float*)d_in[4];
  const float* shp = (const float*)d_in[5];
  const float* pp  = (const float*)d_in[6];
  const float* pt  = (const float*)d_in[7];
  const int* bg = (const int*)d_in[8];
  const int* bs = (const int*)d_in[9];
  float* out = (float*)d_out;
  char* ws = (char*)d_ws;

  int* cntg  = (int*)(ws + OFF_CNT_G);
  int* cnts  = (int*)(ws + OFF_CNT_S);
  int* nb    = (int*)(ws + OFF_NB);
  float* scal = (float*)(ws + OFF_SCAL);
  float* S   = (float*)(ws + OFF_S);
  float* T   = (float*)(ws + OFF_T);
  int* C     = (int*)(ws + OFF_C);
  int* plist = (int*)(ws + OFF_PLIST);
  int* listg = (int*)(ws + OFF_LIST_G);
  int* lists = (int*)(ws + OFF_LIST_S);
  u16* E     = (u16*)(ws + OFF_E);

  k_zero<<<24, 256, 0, stream>>>((u32x4*)ws);
  k_fuseA<<<4864, 256, 0, stream>>>(bg, bs, cntg, cnts, (int*)scal + 3,
                                    listg, lists, gm, scm, scs, shp, pp,
                                    E, nb, plist, scal);
  k_fuseB<<<NTOT_, 256, 0, stream>>>(E, fg, mot, cntg, cnts, listg, lists,
                                     nb, plist, S, T, C, scal);
  k_final<<<1, 256, 0, stream>>>(S, T, C, scal, pp, pt, out);
}

// Round 15
// 199.571 us; speedup vs baseline: 1.0964x; 1.0615x over previous
//
#include <hip/hip_runtime.h>
#include <hip/hip_bf16.h>
#include <stdint.h>

typedef unsigned short u16;
typedef float f32x4 __attribute__((ext_vector_type(4)));
typedef short s16x8 __attribute__((ext_vector_type(8)));
typedef u16   u16x8 __attribute__((ext_vector_type(8)));
typedef u16   u16x4 __attribute__((ext_vector_type(4)));
typedef uint32_t u32x4 __attribute__((ext_vector_type(4)));

#define B_      4096
#define D_      256
#define NA_     131072
#define NM_     32768
#define N2_     8192
#define THR4    6.2499950e-6f   /* (0.05 - 1e-8)^4 */
#define K2E     14.426950408889634f  /* 10*log2(e) */
#define LN2_    0.6931471805599453f
#define CAPG    96
#define CAPS    40

// fuseB role interleave (Bresenham spread): S=segmean G=gemm T=tfix
#define NS_   1024
#define NG_   2080
#define NT_   256
#define NTOT_ 3360
#define NR_   2336   /* NTOT_ - NS_ */

// ---- workspace layout (bytes) ----
#define OFF_CNT_G   0u          // 4096 int
#define OFF_CNT_S   16384u      // 4096 int
#define OFF_NB      32768u      // 4096 int
#define OFF_SCAL    49152u      // f32[0]=llocal f32[1]=lsc int[3]=batch_max
#define OFF_S       65536u      // 8192 f32, atomically accumulated by gemm
#define ZERO_BYTES  98304u      // all of the above zeroed each call
#define OFF_T       98304u      // 8192 f32 (fully written by tfix)
#define OFF_C       131072u     // 8192 int (fully written by tfix)
#define OFF_PLIST   163840u     // 4096*32 int
#define OFF_LIST_G  688128u     // 4096*96 int
#define OFF_LIST_S  2260992u    // 4096*40 int
#define OFF_E       2916352u    // 8192*256 bf16 = 4 MB
#define WS_NEED     7110656u

__device__ inline float wave_sum(float v) {
#pragma unroll
  for (int m = 1; m < 64; m <<= 1) v += __shfl_xor(v, m, 64);
  return v;
}
__device__ inline int wave_sum_i(int v) {
#pragma unroll
  for (int m = 1; m < 64; m <<= 1) v += __shfl_xor(v, m, 64);
  return v;
}
__device__ inline u16 f2bf(float f) {
  uint32_t u = __float_as_uint(f);
  uint32_t r = (u + 0x7FFFu + ((u >> 16) & 1u)) >> 16;
  return (u16)r;
}
__device__ inline float bf2f(u16 v) { return __uint_as_float(((uint32_t)v) << 16); }

// non-temporal f32x4 load: keeps streaming data from evicting E out of L2
__device__ inline f32x4 ldnt4(const float* p) {
  return __builtin_nontemporal_load((const f32x4*)(p));
}

__device__ inline void gload16(const u16* __restrict__ g, u16* l) {
  __builtin_amdgcn_global_load_lds(
      (const __attribute__((address_space(1))) uint32_t*)g,
      (__attribute__((address_space(3))) uint32_t*)l, 16, 0, 0);
}

// ---- zero counters + S ----
__global__ void k_zero(u32x4* __restrict__ p) {
  u32x4 z = {0u, 0u, 0u, 0u};
  p[blockIdx.x * 256 + threadIdx.x] = z;   // 24*256*16B = 98304 B
}

// ---- fuseA: roles interleaved: append (blk%17==0) | pairs | norm | lsc ----
__global__ __launch_bounds__(256) void k_fuseA(
    const int* __restrict__ bg, const int* __restrict__ bs,
    int* __restrict__ cntg, int* __restrict__ cnts, int* __restrict__ bmax,
    int* __restrict__ listg, int* __restrict__ lists,
    const float* __restrict__ gm, const float* __restrict__ scm,
    const float* __restrict__ scs, const float* __restrict__ shp,
    const float* __restrict__ pp,
    u16* __restrict__ E, int* __restrict__ nb, int* __restrict__ plist,
    float* __restrict__ scal) {
  int t = threadIdx.x, w = t >> 6, lane = t & 63;
  int blk = blockIdx.x;   // 8704 total = 512 append + 4096 pairs + 2048 norm + 2048 lsc

  if (blk % 17 == 0) {            // ---- append bucket lists + batch max (512) ----
    int aid = blk / 17;
    int i = aid * 256 + t;
    int b = -1;
    if (i < NA_) {
      b = bg[i];
      int pos = atomicAdd(&cntg[b], 1);
      if (pos < CAPG) listg[b * CAPG + pos] = i;
    }
    if (i < NM_) {
      int b2 = bs[i];
      int pos = atomicAdd(&cnts[b2], 1);
      if (pos < CAPS) lists[b2 * CAPS + pos] = i;
    }
    int m = b;
#pragma unroll
    for (int k = 1; k < 64; k <<= 1) m = max(m, __shfl_xor(m, k, 64));
    if ((t & 63) == 0 && m >= 0) atomicMax(bmax, m);
    return;
  }
  int r1 = blk - blk / 17 - 1;    // rank among non-append, [0,8192)

  if (!(r1 & 1)) {                // ---- pairs (4096) ----
    int a = r1 >> 1;
    f32x4 pa = *(const f32x4*)(pp + (size_t)a * 4);
    for (int b = t; b < B_; b += 256) {
      f32x4 pb = *(const f32x4*)(pp + (size_t)b * 4);
      float dx = pa.x - pb.x, dy = pa.y - pb.y, dz = pa.z - pb.z, dw = pa.w - pb.w;
      float d2 = dx * dx + dy * dy + dz * dz + dw * dw;
      if (d2 < THR4) {
        int pos = atomicAdd(&nb[a], 1);
        if (pos < 32) plist[a * 32 + pos] = b;
      }
    }
    return;
  }
  int r3 = r1 >> 1;               // [0,4096)

  if (!(r3 & 1)) {                // ---- norm -> E bf16 (2048) ----
    int r = (r3 >> 1) * 4 + w;
    const float* src = (r < B_) ? gm + (size_t)r * D_ : scm + (size_t)(r - B_) * D_;
    f32x4 v = ldnt4(src + lane * 4);
    float ss = v.x * v.x + v.y * v.y + v.z * v.z + v.w * v.w;
    ss = wave_sum(ss);
    float inv = 1.f / fmaxf(sqrtf(ss), 1e-12f);
    u16x4 o;
    o.x = f2bf(v.x * inv); o.y = f2bf(v.y * inv);
    o.z = f2bf(v.z * inv); o.w = f2bf(v.w * inv);
    *(u16x4*)(E + (size_t)r * D_ + lane * 4) = o;
  } else {                        // ---- lsc (2048, streaming NT) ----
    int wg = (r3 >> 1) * 4 + w;
    float acc = 0.f;
    for (int r = wg; r < NM_; r += 8192) {
      f32x4 va = ldnt4(scs + (size_t)r * D_ + lane * 4);
      f32x4 vb = ldnt4(shp + (size_t)r * D_ + lane * 4);
      float dx = va.x - vb.x, dy = va.y - vb.y, dz = va.z - vb.z, dw = va.w - vb.w;
      float ss = wave_sum(dx * dx + dy * dy + dz * dz + dw * dw);
      if (lane == 0) acc += sqrtf(ss);
    }
    __shared__ float sr4[4];
    if (lane == 0) sr4[w] = acc;
    __syncthreads();
    if (t == 0) atomicAdd(&scal[1], sr4[0] + sr4[1] + sr4[2] + sr4[3]);
  }
}

// ---- wave-autonomous segmented mean gather (NT row loads) ----
__device__ inline void wave_row_sum(const float* __restrict__ src,
                                    const int* __restrict__ list,
                                    int off, int cnt, int lane, f32x4* accs) {
  f32x4 a0 = {0.f,0.f,0.f,0.f}, a1 = a0, a2 = a0, a3 = a0;
  f32x4 a4 = a0, a5 = a0, a6 = a0, a7 = a0;
  for (int base = 0; base < cnt; base += 64) {
    int n = min(cnt - base, 64);
    int idx = (lane < n) ? list[off + base + lane] : 0;
    int k = 0;
    for (; k + 7 < n; k += 8) {
      int i0 = __shfl(idx, k,     64), i1 = __shfl(idx, k + 1, 64);
      int i2 = __shfl(idx, k + 2, 64), i3 = __shfl(idx, k + 3, 64);
      int i4 = __shfl(idx, k + 4, 64), i5 = __shfl(idx, k + 5, 64);
      int i6 = __shfl(idx, k + 6, 64), i7 = __shfl(idx, k + 7, 64);
      a0 += ldnt4(src + (size_t)i0 * D_ + lane * 4);
      a1 += ldnt4(src + (size_t)i1 * D_ + lane * 4);
      a2 += ldnt4(src + (size_t)i2 * D_ + lane * 4);
      a3 += ldnt4(src + (size_t)i3 * D_ + lane * 4);
      a4 += ldnt4(src + (size_t)i4 * D_ + lane * 4);
      a5 += ldnt4(src + (size_t)i5 * D_ + lane * 4);
      a6 += ldnt4(src + (size_t)i6 * D_ + lane * 4);
      a7 += ldnt4(src + (size_t)i7 * D_ + lane * 4);
    }
    for (; k < n; k++) {
      int i0 = __shfl(idx, k, 64);
      a0 += ldnt4(src + (size_t)i0 * D_ + lane * 4);
    }
  }
  *accs = ((a0 + a1) + (a2 + a3)) + ((a4 + a5) + (a6 + a7));
}

// ---- fuseB: segmean | gemm (BK=32, 16.6KB LDS) | tfix, Bresenham-interleaved ----
__global__ __launch_bounds__(256) void k_fuseB(
    const u16* __restrict__ E,
    const float* __restrict__ fg, const float* __restrict__ fm,
    const int* __restrict__ cntg, const int* __restrict__ cnts,
    const int* __restrict__ listg, const int* __restrict__ lists,
    const int* __restrict__ nb, const int* __restrict__ plist,
    float* __restrict__ S, float* __restrict__ T, int* __restrict__ C,
    float* __restrict__ scal) {
  __shared__ __align__(16) u16 As[128 * 32];   // 8 KB
  __shared__ __align__(16) u16 Bs[128 * 32];   // 8 KB
  int blk = blockIdx.x;
  int tid = threadIdx.x, lane = tid & 63, wid = tid >> 6;

  int64_t p = (int64_t)blk * NS_;
  int srem = (int)(p % NTOT_);
  if (srem < NS_) {               // ---- segmean ----
    int sid = (int)(p / NTOT_);
    int b = sid * 4 + wid;
    int cg = cntg[b], cs = cnts[b];
    f32x4 sg, ss;
    wave_row_sum(fg, listg, b * CAPG, min(cg, CAPG), lane, &sg);
    wave_row_sum(fm, lists, b * CAPS, min(cs, CAPS), lane, &ss);
    float ig = 1.f / fmaxf((float)cg, 1.f);
    float is = 1.f / fmaxf((float)cs, 1.f);
    float dx = sg.x * ig - ss.x * is, dy = sg.y * ig - ss.y * is;
    float dz = sg.z * ig - ss.z * is, dw = sg.w * ig - ss.w * is;
    float v = wave_sum(dx * dx + dy * dy + dz * dz + dw * dw);
    __shared__ float r2[4];
    if (lane == 0) r2[wid] = (cg > 0 && cs > 0) ? sqrtf(v) : 0.f;
    __syncthreads();
    if (tid == 0) {
      float s = r2[0] + r2[1] + r2[2] + r2[3];
      if (s != 0.f) atomicAdd(&scal[0], s);
    }
    return;
  }

  int r = blk - (int)((p + NTOT_ - 1) / NTOT_);   // rank among non-S
  int64_t q = (int64_t)r * NG_;
  int grem = (int)(q % NR_);

  if (grem >= NG_) {              // ---- tfix (8 rows/wave) ----
    int tix = r - (int)((q + NR_ - 1) / NR_);
#pragma unroll
    for (int k8 = 0; k8 < 8; k8++) {
      int i = tix * 32 + wid * 8 + k8;
      int a = i & (B_ - 1);
      int n = min(nb[a], 32);
      u16x4 vi = *(const u16x4*)(E + (size_t)i * D_ + lane * 4);
      float ex = bf2f(vi.x), ey = bf2f(vi.y), ez = bf2f(vi.z), ew = bf2f(vi.w);
      float acc = -(ex * ex + ey * ey + ez * ez + ew * ew);
      for (int k = 0; k < n; k++) {
        int b = plist[a * 32 + k];
        u16x4 v1 = *(const u16x4*)(E + (size_t)b * D_ + lane * 4);
        u16x4 v2 = *(const u16x4*)(E + (size_t)(b + B_) * D_ + lane * 4);
        acc += ex * bf2f(v1.x) + ey * bf2f(v1.y) + ez * bf2f(v1.z) + ew * bf2f(v1.w);
        acc += ex * bf2f(v2.x) + ey * bf2f(v2.y) + ez * bf2f(v2.z) + ew * bf2f(v2.w);
      }
      acc = wave_sum(acc);
      if (lane == 0) { T[i] = 10.0f * acc; C[i] = 2 * n - 1; }
    }
    return;
  }

  // ---- gemm: triangular 128x128 tile, BK=32 chunks, global_load_lds staging ----
  int t = (int)(q / NR_);
  int bi = (int)((129.0f - sqrtf(129.0f * 129.0f - 8.0f * (float)t)) * 0.5f);
  while ((bi + 1) * (129 - (bi + 1)) / 2 <= t) bi++;
  while (bi * (129 - bi) / 2 > t) bi--;
  int bj = bi + (t - bi * (129 - bi) / 2);

  int row0 = bi * 128, col0 = bj * 128;
  int wr = wid >> 1, wc = wid & 1;

  // staging geometry: segment s (0..7) = 16 rows x 64B; lane -> row s*16+(lane>>2),
  // col bytes (lane&3)*16, source pre-swizzled by ((row&3)<<4)
  int rsub = lane >> 2;                               // 0..15
  int csw  = (((lane & 3) ^ (rsub & 3)) << 3);        // swizzled col in u16 units

  f32x4 acc[4][4];
#pragma unroll
  for (int mi = 0; mi < 4; mi++)
#pragma unroll
    for (int ni = 0; ni < 4; ni++) {
      f32x4 z = {0.f, 0.f, 0.f, 0.f};
      acc[mi][ni] = z;
    }

  for (int kc = 0; kc < 8; ++kc) {
    __syncthreads();
#pragma unroll
    for (int it = 0; it < 2; it++) {
      int s = wid * 2 + it;                           // 0..7
      int rr = s * 16 + rsub;
      gload16(E + (size_t)(row0 + rr) * D_ + kc * 32 + csw, As + s * 512);
      gload16(E + (size_t)(col0 + rr) * D_ + kc * 32 + csw, Bs + s * 512);
    }
    __syncthreads();
    s16x8 af[4], bfr[4];
#pragma unroll
    for (int mi = 0; mi < 4; mi++) {
      int rA = wr * 64 + mi * 16 + (lane & 15);
      int addr = rA * 64 + (((lane >> 4) * 16) ^ ((rA & 3) << 4));
      af[mi] = *(const s16x8*)((const char*)As + addr);
    }
#pragma unroll
    for (int ni = 0; ni < 4; ni++) {
      int rB = wc * 64 + ni * 16 + (lane & 15);
      int addr = rB * 64 + (((lane >> 4) * 16) ^ ((rB & 3) << 4));
      bfr[ni] = *(const s16x8*)((const char*)Bs + addr);
    }
#pragma unroll
    for (int mi = 0; mi < 4; mi++)
#pragma unroll
      for (int ni = 0; ni < 4; ni++)
        acc[mi][ni] = __builtin_amdgcn_mfma_f32_16x16x32_bf16(af[mi], bfr[ni], acc[mi][ni], 0, 0, 0);
  }

  // epilogue: exp(10a-10)=exp2(a*K2E-K2E); rows + (off-diag) cols -> atomic S
  int g = lane >> 4, cl = lane & 15;
  float colsum[4] = {0.f, 0.f, 0.f, 0.f};
#pragma unroll
  for (int mi = 0; mi < 4; mi++) {
#pragma unroll
    for (int reg = 0; reg < 4; ++reg) {
      int gi = row0 + wr * 64 + mi * 16 + g * 4 + reg;
      float vs = 0.f;
#pragma unroll
      for (int ni = 0; ni < 4; ni++) {
        float e = exp2f(acc[mi][ni][reg] * K2E - K2E);
        vs += e;
        colsum[ni] += e;
      }
#pragma unroll
      for (int m = 1; m < 16; m <<= 1) vs += __shfl_xor(vs, m, 64);
      if (cl == 0) atomicAdd(&S[gi], vs);
    }
  }
  if (bi != bj) {
#pragma unroll
    for (int ni = 0; ni < 4; ni++) {
      float cs = colsum[ni];
      cs += __shfl_xor(cs, 16, 64);
      cs += __shfl_xor(cs, 32, 64);
      if (g == 0) atomicAdd(&S[col0 + wc * 64 + ni * 16 + cl], cs);
    }
  }
}

// ---- final combine (+ l_prop fused) ----
__global__ void k_final(const float* __restrict__ S, const float* __restrict__ T,
                        const int* __restrict__ C, const float* __restrict__ scal,
                        const float* __restrict__ pp, const float* __restrict__ pt,
                        float* __restrict__ out) {
  float sp = 0.f;
  for (int i = threadIdx.x; i < B_ * 4; i += 256) {
    float d = pp[i] - pt[i];
    sp += d * d;
  }
  float rls = 0.f; int nv = 0;
  for (int i = threadIdx.x; i < N2_; i += 256) {
    int ci = C[i];
    if (ci > 0) { rls += (10.0f + __log2f(S[i]) * LN2_) - T[i] / (float)ci; nv++; }
  }
  rls = wave_sum(rls);
  sp  = wave_sum(sp);
  nv  = wave_sum_i(nv);
  __shared__ float r1[4], r3[4]; __shared__ int r2[4];
  int lane = threadIdx.x & 63, w = threadIdx.x >> 6;
  if (lane == 0) { r1[w] = rls; r2[w] = nv; r3[w] = sp; }
  __syncthreads();
  if (threadIdx.x == 0) {
    float rtot = r1[0] + r1[1] + r1[2] + r1[3];
    int nvt = r2[0] + r2[1] + r2[2] + r2[3];
    float sptot = r3[0] + r3[1] + r3[2] + r3[3];
    float l_contr = nvt > 0 ? rtot / (float)nvt : 0.f;
    int bmax = ((const int*)scal)[3];
    float bs = (float)bmax + 1.0f;
    float l_local_g = scal[0] / bs;
    float l_sc = scal[1] / (float)NM_;
    float l_prop = sptot / (float)(B_ * 4);
    float l_hes = 1.0f * l_local_g + 0.8f * l_contr + 1.0f * l_sc + 0.8f * l_contr + 0.5f * l_prop;
    out[0] = l_hes; out[1] = l_local_g; out[2] = l_contr;
    out[3] = l_sc;  out[4] = l_contr;   out[5] = l_prop;
  }
}

extern "C" void kernel_launch(void* const* d_in, const int* in_sizes, int n_in,
                              void* d_out, int out_size, void* d_ws, size_t ws_size,
                              hipStream_t stream) {
  if (ws_size < WS_NEED) return;
  const float* gm  = (const float*)d_in[0];
  const float* fg  = (const float*)d_in[1];
  const float* scm = (const float*)d_in[2];
  const float* scs = (const float*)d_in[3];
  const float* mot = (const float*)d_in[4];
  const float* shp = (const float*)d_in[5];
  const float* pp  = (const float*)d_in[6];
  const float* pt  = (const float*)d_in[7];
  const int* bg = (const int*)d_in[8];
  const int* bs = (const int*)d_in[9];
  float* out = (float*)d_out;
  char* ws = (char*)d_ws;

  int* cntg  = (int*)(ws + OFF_CNT_G);
  int* cnts  = (int*)(ws + OFF_CNT_S);
  int* nb    = (int*)(ws + OFF_NB);
  float* scal = (float*)(ws + OFF_SCAL);
  float* S   = (float*)(ws + OFF_S);
  float* T   = (float*)(ws + OFF_T);
  int* C     = (int*)(ws + OFF_C);
  int* plist = (int*)(ws + OFF_PLIST);
  int* listg = (int*)(ws + OFF_LIST_G);
  int* lists = (int*)(ws + OFF_LIST_S);
  u16* E     = (u16*)(ws + OFF_E);

  k_zero<<<24, 256, 0, stream>>>((u32x4*)ws);
  k_fuseA<<<8704, 256, 0, stream>>>(bg, bs, cntg, cnts, (int*)scal + 3,
                                    listg, lists, gm, scm, scs, shp, pp,
                                    E, nb, plist, scal);
  k_fuseB<<<NTOT_, 256, 0, stream>>>(E, fg, mot, cntg, cnts, listg, lists,
                                     nb, plist, S, T, C, scal);
  k_final<<<1, 256, 0, stream>>>(S, T, C, scal, pp, pt, out);
}